// Round 5
// baseline (500.619 us; speedup 1.0000x reference)
//
#include <hip/hip_runtime.h>
#include <math.h>

#define N_NODES 50000
#define N_EDGES 800000
#define NFEAT 256
#define NHID 64
#define NCLASS 2

// dst buckets: node>>7 -> 391 buckets of 128 nodes
#define DB 128
#define NDB 391
#define BCAP_D 3072      // mean 2048, sigma 45 -> 22 sigma headroom
#define DBP 129          // padded accumulator stride (odd -> bank spread)
// src buckets: node>>8 -> 196 buckets (out-degree hist only)
#define NSB 196
#define BCAP_S 8192      // mean 4081, sigma 64 -> 64 sigma
#define EPB 4096         // edges per scatter block (16/thread)
#define NB_EDGE ((N_EDGES + EPB - 1) / EPB)  // 196

// ---------------- workspace layout (4-byte units) ----------------
#define OFF_CURD 0        // int[512]  dst-bucket cursors (memset 0)
#define OFF_CURS 512      // int[256]  src-bucket cursors (memset 0)
#define OFF_NSRC 768      // f32[50000]
#define OFF_NDST 50768    // f32[50000]
#define OFF_DPK  100768   // int[391*3072] packed (src<<7|dst&127) by dst>>7
#define OFF_SV8  1301920  // uchar[196*8192] (src&255) by src>>8 = 401408 words
#define OFF_HB   1703328  // bf16[50000*64] = 1600000 words (16B-aligned base)
#define OFF_H2   3303328  // f32[100000]

typedef __attribute__((ext_vector_type(8))) short bf16x8;
typedef __attribute__((ext_vector_type(4))) float f32x4;

static __device__ __forceinline__ unsigned short f2bf(float f) {
    union { float f; unsigned int u; } v; v.f = f;
    unsigned int u = v.u + 0x7fffu + ((v.u >> 16) & 1u);  // RNE
    return (unsigned short)(u >> 16);
}
static __device__ __forceinline__ float bflo(unsigned int u) {
    union { unsigned int x; float f; } v; v.x = u << 16; return v.f;
}
static __device__ __forceinline__ float bfhi(unsigned int u) {
    union { unsigned int x; float f; } v; v.x = u & 0xffff0000u; return v.f;
}

// K1: partition edges into fixed-capacity dst-buckets (packed src<<7|dstlow)
// and src-buckets (src&255 bytes). LDS hist -> one global atomic per bucket.
__global__ __launch_bounds__(256) void bscatter_kernel(const int* __restrict__ src,
                                                       const int* __restrict__ dst,
                                                       int* __restrict__ cur_d,
                                                       int* __restrict__ cur_s,
                                                       int* __restrict__ dpk,
                                                       unsigned char* __restrict__ sv8) {
    __shared__ int hd[512], bd[512], cd[512], hs[256], bs[256], cs[256];
    int t = threadIdx.x;
    hd[t] = 0; hd[t + 256] = 0; cd[t] = 0; cd[t + 256] = 0;
    hs[t] = 0; cs[t] = 0;
    __syncthreads();
    int base = blockIdx.x * EPB;
    int ls[16], ld[16];
#pragma unroll
    for (int i = 0; i < 16; ++i) {
        int e = base + t + i * 256;
        ls[i] = (e < N_EDGES) ? src[e] : -1;
        ld[i] = (e < N_EDGES) ? dst[e] : -1;
        if (ld[i] >= 0) {
            atomicAdd(&hd[ld[i] >> 7], 1);
            atomicAdd(&hs[ls[i] >> 8], 1);
        }
    }
    __syncthreads();
    if (hd[t]) bd[t] = atomicAdd(&cur_d[t], hd[t]);
    if (hd[t + 256]) bd[t + 256] = atomicAdd(&cur_d[t + 256], hd[t + 256]);
    if (hs[t]) bs[t] = atomicAdd(&cur_s[t], hs[t]);
    __syncthreads();
#pragma unroll
    for (int i = 0; i < 16; ++i) {
        if (ld[i] >= 0) {
            int bin = ld[i] >> 7;
            int pos = bd[bin] + atomicAdd(&cd[bin], 1);
            dpk[bin * BCAP_D + pos] = (ls[i] << 7) | (ld[i] & 127);
            int sbin = ls[i] >> 8;
            int spos = bs[sbin] + atomicAdd(&cs[sbin], 1);
            sv8[sbin * BCAP_S + spos] = (unsigned char)(ls[i] & 255);
        }
    }
}

// K2: per src-bucket: out-degree hist -> norm_src
__global__ __launch_bounds__(256) void sfin_kernel(const int* __restrict__ cur_s,
                                                   const unsigned char* __restrict__ sv8,
                                                   float* __restrict__ norm_src) {
    __shared__ int hist[256];
    int b = blockIdx.x, t = threadIdx.x;
    hist[t] = 0;
    __syncthreads();
    int cnt = cur_s[b];
    int base = b * BCAP_S;
    for (int j = t; j < cnt; j += 256) atomicAdd(&hist[sv8[base + j]], 1);
    __syncthreads();
    int gid = b * 256 + t;
    if (gid < N_NODES) norm_src[gid] = rsqrtf(fmaxf((float)hist[t], 1.0f));
}

// K3: h_bf16[50000x64] = bf16( (x * norm_src[:,None]) @ W1[256x64] ), MFMA
#define LDA 264
__global__ __launch_bounds__(256) void gemm1_kernel(const float* __restrict__ x,
                                                    const float* __restrict__ W1,
                                                    const float* __restrict__ norm_src,
                                                    unsigned short* __restrict__ hb) {
    __shared__ unsigned short As[64][LDA];
    __shared__ unsigned short Bs[64][LDA];
    const int t = threadIdx.x;
    const int row0 = blockIdx.x * 64;
#pragma unroll
    for (int i = 0; i < 16; ++i) {
        int f = i * 256 + t;
        int r = f >> 6;
        int c4 = (f & 63) * 4;
        int grow = row0 + r;
        float4 av = make_float4(0.f, 0.f, 0.f, 0.f);
        float nrm = 0.f;
        if (grow < N_NODES) {
            av = *(const float4*)(&x[(size_t)grow * NFEAT + c4]);
            nrm = norm_src[grow];
        }
        ushort4 o;
        o.x = f2bf(av.x * nrm); o.y = f2bf(av.y * nrm);
        o.z = f2bf(av.z * nrm); o.w = f2bf(av.w * nrm);
        *(ushort4*)(&As[r][c4]) = o;
    }
#pragma unroll
    for (int i = 0; i < 16; ++i) {
        int f = i * 256 + t;
        int k = f >> 4;
        int n4 = (f & 15) * 4;
        float4 wv = *(const float4*)(&W1[k * NHID + n4]);
        Bs[n4 + 0][k] = f2bf(wv.x);
        Bs[n4 + 1][k] = f2bf(wv.y);
        Bs[n4 + 2][k] = f2bf(wv.z);
        Bs[n4 + 3][k] = f2bf(wv.w);
    }
    __syncthreads();
    const int w = t >> 6;
    const int l = t & 63;
    const int m = l & 15;
    const int kq = (l >> 4) * 8;
    f32x4 acc[4] = {{0.f, 0.f, 0.f, 0.f}, {0.f, 0.f, 0.f, 0.f},
                    {0.f, 0.f, 0.f, 0.f}, {0.f, 0.f, 0.f, 0.f}};
#pragma unroll
    for (int c8 = 0; c8 < 8; ++c8) {
        int k0 = c8 * 32 + kq;
        bf16x8 a = *(const bf16x8*)(&As[w * 16 + m][k0]);
#pragma unroll
        for (int ct = 0; ct < 4; ++ct) {
            bf16x8 b = *(const bf16x8*)(&Bs[ct * 16 + m][k0]);
            acc[ct] = __builtin_amdgcn_mfma_f32_16x16x32_bf16(a, b, acc[ct], 0, 0, 0);
        }
    }
    const int q = l >> 4;
#pragma unroll
    for (int ct = 0; ct < 4; ++ct) {
#pragma unroll
        for (int reg = 0; reg < 4; ++reg) {
            int r = row0 + w * 16 + q * 4 + reg;
            if (r < N_NODES) hb[(size_t)r * NHID + ct * 16 + m] = f2bf(acc[ct][reg]);
        }
    }
}

// K4: fused layer1, bucket-major. Block = one 128-node dst bucket.
// LDS accT[feat][node] (transposed, stride 129). Wave: 8 edges/iter via
// dwordx4 (8 lanes x 16B = one 128B bf16 row), 8 ds_add_f32 each.
// Epilogue: deg->norm_dst, relu(agg*nd+b1)*ns @ W2 -> h2.
__global__ __launch_bounds__(256) void fused1_kernel(const int* __restrict__ cur_d,
                                                     const int* __restrict__ dpk,
                                                     const unsigned short* __restrict__ hb,
                                                     const float* __restrict__ norm_src,
                                                     const float* __restrict__ b1,
                                                     const float* __restrict__ W2,
                                                     float* __restrict__ norm_dst,
                                                     float* __restrict__ h2) {
    __shared__ float accT[64 * DBP];  // 33024 B
    __shared__ int hist[DB];
    __shared__ float b1s[64], w2s[128];
    int t = threadIdx.x, b = blockIdx.x;
    for (int i = t; i < 64 * DBP; i += 256) accT[i] = 0.f;
    if (t < DB) hist[t] = 0;
    if (t < 64) b1s[t] = b1[t];
    else if (t < 192) w2s[t - 64] = W2[t - 64];
    __syncthreads();
    int cnt = cur_d[b];
    const int* bucket = dpk + b * BCAP_D;
    int w = t >> 6, l = t & 63, e8 = l >> 3, fg = l & 7;
    for (int base = w * 8; base < cnt; base += 32) {
        int j = base + e8;
        if (j < cnt) {
            int pk = bucket[j];
            int s = ((unsigned)pk) >> 7;
            int dlow = pk & 127;
            uint4 u = *(const uint4*)(&hb[(size_t)s * NHID + fg * 8]);
            int a0 = (fg * 8) * DBP + dlow;
            atomicAdd(&accT[a0 + 0 * DBP], bflo(u.x));
            atomicAdd(&accT[a0 + 1 * DBP], bfhi(u.x));
            atomicAdd(&accT[a0 + 2 * DBP], bflo(u.y));
            atomicAdd(&accT[a0 + 3 * DBP], bfhi(u.y));
            atomicAdd(&accT[a0 + 4 * DBP], bflo(u.z));
            atomicAdd(&accT[a0 + 5 * DBP], bfhi(u.z));
            atomicAdd(&accT[a0 + 6 * DBP], bflo(u.w));
            atomicAdd(&accT[a0 + 7 * DBP], bfhi(u.w));
            if (fg == 0) atomicAdd(&hist[dlow], 1);
        }
    }
    __syncthreads();
    if (t < DB) {
        int gnode = b * DB + t;
        if (gnode < N_NODES) {
            float nd = rsqrtf(fmaxf((float)hist[t], 1.0f));
            norm_dst[gnode] = nd;
            float ns = norm_src[gnode];
            float p0 = 0.f, p1 = 0.f;
#pragma unroll
            for (int f = 0; f < 64; ++f) {
                float h1 = fmaxf(fmaf(accT[f * DBP + t], nd, b1s[f]), 0.f) * ns;
                p0 = fmaf(h1, w2s[f * 2], p0);
                p1 = fmaf(h1, w2s[f * 2 + 1], p1);
            }
            *(float2*)(&h2[gnode * 2]) = make_float2(p0, p1);
        }
    }
}

// K5: fused layer2, bucket-major: stream bucket edges, gather h2[src] (8B,
// L2-resident), ds_add into 128x2 LDS tile, log_softmax epilogue.
__global__ __launch_bounds__(256) void fused2_kernel(const int* __restrict__ cur_d,
                                                     const int* __restrict__ dpk,
                                                     const float* __restrict__ h2,
                                                     const float* __restrict__ norm_dst,
                                                     const float* __restrict__ b2,
                                                     float* __restrict__ out) {
    __shared__ float acc2[DB * 2];
    int t = threadIdx.x, b = blockIdx.x;
    acc2[t] = 0.f;  // 256 = DB*2
    __syncthreads();
    int cnt = cur_d[b];
    const int* bucket = dpk + b * BCAP_D;
    for (int j = t; j < cnt; j += 256) {
        int pk = bucket[j];
        int s = ((unsigned)pk) >> 7;
        int dlow = pk & 127;
        float2 v = *(const float2*)(&h2[s * 2]);
        atomicAdd(&acc2[dlow * 2 + 0], v.x);
        atomicAdd(&acc2[dlow * 2 + 1], v.y);
    }
    __syncthreads();
    if (t < DB) {
        int gnode = b * DB + t;
        if (gnode < N_NODES) {
            float nd = norm_dst[gnode];
            float l0 = fmaf(acc2[t * 2 + 0], nd, b2[0]);
            float l1 = fmaf(acc2[t * 2 + 1], nd, b2[1]);
            float m = fmaxf(l0, l1);
            float lse = m + logf(expf(l0 - m) + expf(l1 - m));
            *(float2*)(&out[gnode * 2]) = make_float2(l0 - lse, l1 - lse);
        }
    }
}

extern "C" void kernel_launch(void* const* d_in, const int* in_sizes, int n_in,
                              void* d_out, int out_size, void* d_ws, size_t ws_size,
                              hipStream_t stream) {
    const float* x  = (const float*)d_in[0];
    const int* src  = (const int*)d_in[1];
    const int* dst  = (const int*)d_in[2];
    const float* W1 = (const float*)d_in[3];
    const float* b1 = (const float*)d_in[4];
    const float* W2 = (const float*)d_in[5];
    const float* b2 = (const float*)d_in[6];
    float* out = (float*)d_out;
    float* ws  = (float*)d_ws;
    int*   wsi = (int*)d_ws;

    int*   cur_d    = wsi + OFF_CURD;
    int*   cur_s    = wsi + OFF_CURS;
    float* norm_src = ws + OFF_NSRC;
    float* norm_dst = ws + OFF_NDST;
    int*   dpk      = wsi + OFF_DPK;
    unsigned char* sv8 = (unsigned char*)(wsi + OFF_SV8);
    unsigned short* hb = (unsigned short*)(wsi + OFF_HB);
    float* h2       = ws + OFF_H2;

    hipMemsetAsync(cur_d, 0, 768 * sizeof(int), stream);
    bscatter_kernel<<<NB_EDGE, 256, 0, stream>>>(src, dst, cur_d, cur_s, dpk, sv8);
    sfin_kernel<<<NSB, 256, 0, stream>>>(cur_s, sv8, norm_src);
    gemm1_kernel<<<(N_NODES + 63) / 64, 256, 0, stream>>>(x, W1, norm_src, hb);
    fused1_kernel<<<NDB, 256, 0, stream>>>(cur_d, dpk, hb, norm_src, b1, W2, norm_dst, h2);
    fused2_kernel<<<NDB, 256, 0, stream>>>(cur_d, dpk, h2, norm_dst, b2, out);
}

// Round 6
// 455.481 us; speedup vs baseline: 1.0991x; 1.0991x over previous
//
#include <hip/hip_runtime.h>
#include <math.h>

#define N_NODES 50000
#define N_EDGES 800000
#define NFEAT 256
#define NHID 64
#define NCLASS 2

// dst buckets: node>>5 -> 1563 buckets of 32 nodes  (R5 post-mortem: 391
// blocks = 1 block/CU = 12.5% occupancy killed it; 1563 blocks -> ~6/CU)
#define DB 32
#define NDB 1563
#define BCAP_D 768       // mean 512, sigma 23 -> 11 sigma headroom
#define DBP 33           // padded accumulator stride
// src buckets: node>>8 -> 196 buckets (out-degree hist only)
#define NSB 196
#define BCAP_S 8192
#define EPB 4096         // edges per scatter block (16/thread)
#define NB_EDGE ((N_EDGES + EPB - 1) / EPB)  // 196

// ---------------- workspace layout (4-byte units) ----------------
#define OFF_CURD 0        // int[1600]  dst-bucket cursors (memset 0)
#define OFF_CURS 1600     // int[256]   src-bucket cursors (memset 0)
#define OFF_NSRC 1856     // f32[50000]
#define OFF_NDST 51856    // f32[50000]
#define OFF_DPK  101856   // int[1563*768] packed (src<<5|dst&31) by dst>>5
#define OFF_SV8  1302240  // uchar[196*8192] (src&255) by src>>8 = 401408 words
#define OFF_HB   1703648  // bf16[50000*64] = 1600000 words (16B-aligned)
#define OFF_H2   3303648  // f32[100000]

typedef __attribute__((ext_vector_type(8))) short bf16x8;
typedef __attribute__((ext_vector_type(4))) float f32x4;

static __device__ __forceinline__ unsigned short f2bf(float f) {
    union { float f; unsigned int u; } v; v.f = f;
    unsigned int u = v.u + 0x7fffu + ((v.u >> 16) & 1u);  // RNE
    return (unsigned short)(u >> 16);
}
static __device__ __forceinline__ float bflo(unsigned int u) {
    union { unsigned int x; float f; } v; v.x = u << 16; return v.f;
}
static __device__ __forceinline__ float bfhi(unsigned int u) {
    union { unsigned int x; float f; } v; v.x = u & 0xffff0000u; return v.f;
}

// K1: partition edges into fixed-capacity dst-buckets (packed src<<5|dstlow)
// and src-buckets (src&255 bytes). LDS hist -> one global atomic per bucket.
__global__ __launch_bounds__(256) void bscatter_kernel(const int* __restrict__ src,
                                                       const int* __restrict__ dst,
                                                       int* __restrict__ cur_d,
                                                       int* __restrict__ cur_s,
                                                       int* __restrict__ dpk,
                                                       unsigned char* __restrict__ sv8) {
    __shared__ int hd[NDB], bd[NDB], cd[NDB], hs[256], bs[256], cs[256];
    int t = threadIdx.x;
    for (int i = t; i < NDB; i += 256) { hd[i] = 0; cd[i] = 0; }
    hs[t] = 0; cs[t] = 0;
    __syncthreads();
    int base = blockIdx.x * EPB;
    int ls[16], ld[16];
#pragma unroll
    for (int i = 0; i < 16; ++i) {
        int e = base + t + i * 256;
        ls[i] = (e < N_EDGES) ? src[e] : -1;
        ld[i] = (e < N_EDGES) ? dst[e] : -1;
        if (ld[i] >= 0) {
            atomicAdd(&hd[ld[i] >> 5], 1);
            atomicAdd(&hs[ls[i] >> 8], 1);
        }
    }
    __syncthreads();
    for (int i = t; i < NDB; i += 256)
        if (hd[i]) bd[i] = atomicAdd(&cur_d[i], hd[i]);
    if (hs[t]) bs[t] = atomicAdd(&cur_s[t], hs[t]);
    __syncthreads();
#pragma unroll
    for (int i = 0; i < 16; ++i) {
        if (ld[i] >= 0) {
            int bin = ld[i] >> 5;
            int pos = bd[bin] + atomicAdd(&cd[bin], 1);
            dpk[bin * BCAP_D + pos] = (ls[i] << 5) | (ld[i] & 31);
            int sbin = ls[i] >> 8;
            int spos = bs[sbin] + atomicAdd(&cs[sbin], 1);
            sv8[sbin * BCAP_S + spos] = (unsigned char)(ls[i] & 255);
        }
    }
}

// K2: per src-bucket: out-degree hist -> norm_src
__global__ __launch_bounds__(256) void sfin_kernel(const int* __restrict__ cur_s,
                                                   const unsigned char* __restrict__ sv8,
                                                   float* __restrict__ norm_src) {
    __shared__ int hist[256];
    int b = blockIdx.x, t = threadIdx.x;
    hist[t] = 0;
    __syncthreads();
    int cnt = cur_s[b];
    int base = b * BCAP_S;
    for (int j = t; j < cnt; j += 256) atomicAdd(&hist[sv8[base + j]], 1);
    __syncthreads();
    int gid = b * 256 + t;
    if (gid < N_NODES) norm_src[gid] = rsqrtf(fmaxf((float)hist[t], 1.0f));
}

// K3: h_bf16[50000x64] = bf16( (x * norm_src[:,None]) @ W1[256x64] ), MFMA
#define LDA 264
__global__ __launch_bounds__(256) void gemm1_kernel(const float* __restrict__ x,
                                                    const float* __restrict__ W1,
                                                    const float* __restrict__ norm_src,
                                                    unsigned short* __restrict__ hb) {
    __shared__ unsigned short As[64][LDA];
    __shared__ unsigned short Bs[64][LDA];
    const int t = threadIdx.x;
    const int row0 = blockIdx.x * 64;
#pragma unroll
    for (int i = 0; i < 16; ++i) {
        int f = i * 256 + t;
        int r = f >> 6;
        int c4 = (f & 63) * 4;
        int grow = row0 + r;
        float4 av = make_float4(0.f, 0.f, 0.f, 0.f);
        float nrm = 0.f;
        if (grow < N_NODES) {
            av = *(const float4*)(&x[(size_t)grow * NFEAT + c4]);
            nrm = norm_src[grow];
        }
        ushort4 o;
        o.x = f2bf(av.x * nrm); o.y = f2bf(av.y * nrm);
        o.z = f2bf(av.z * nrm); o.w = f2bf(av.w * nrm);
        *(ushort4*)(&As[r][c4]) = o;
    }
#pragma unroll
    for (int i = 0; i < 16; ++i) {
        int f = i * 256 + t;
        int k = f >> 4;
        int n4 = (f & 15) * 4;
        float4 wv = *(const float4*)(&W1[k * NHID + n4]);
        Bs[n4 + 0][k] = f2bf(wv.x);
        Bs[n4 + 1][k] = f2bf(wv.y);
        Bs[n4 + 2][k] = f2bf(wv.z);
        Bs[n4 + 3][k] = f2bf(wv.w);
    }
    __syncthreads();
    const int w = t >> 6;
    const int l = t & 63;
    const int m = l & 15;
    const int kq = (l >> 4) * 8;
    f32x4 acc[4] = {{0.f, 0.f, 0.f, 0.f}, {0.f, 0.f, 0.f, 0.f},
                    {0.f, 0.f, 0.f, 0.f}, {0.f, 0.f, 0.f, 0.f}};
#pragma unroll
    for (int c8 = 0; c8 < 8; ++c8) {
        int k0 = c8 * 32 + kq;
        bf16x8 a = *(const bf16x8*)(&As[w * 16 + m][k0]);
#pragma unroll
        for (int ct = 0; ct < 4; ++ct) {
            bf16x8 b = *(const bf16x8*)(&Bs[ct * 16 + m][k0]);
            acc[ct] = __builtin_amdgcn_mfma_f32_16x16x32_bf16(a, b, acc[ct], 0, 0, 0);
        }
    }
    const int q = l >> 4;
#pragma unroll
    for (int ct = 0; ct < 4; ++ct) {
#pragma unroll
        for (int reg = 0; reg < 4; ++reg) {
            int r = row0 + w * 16 + q * 4 + reg;
            if (r < N_NODES) hb[(size_t)r * NHID + ct * 16 + m] = f2bf(acc[ct][reg]);
        }
    }
}

// K4: fused layer1, bucket-major. Block = one 32-node dst bucket (~512 edges).
// Wave: 8 edges/iter via dwordx4 (8 lanes x 16B = one 128B bf16 row), 8
// ds_add_f32 each. Epilogue: deg->norm_dst, relu(agg*nd+b1)*ns @ W2 -> h2.
__global__ __launch_bounds__(256) void fused1_kernel(const int* __restrict__ cur_d,
                                                     const int* __restrict__ dpk,
                                                     const unsigned short* __restrict__ hb,
                                                     const float* __restrict__ norm_src,
                                                     const float* __restrict__ b1,
                                                     const float* __restrict__ W2,
                                                     float* __restrict__ norm_dst,
                                                     float* __restrict__ h2) {
    __shared__ float accT[64 * DBP];  // 8448 B
    __shared__ int hist[DB];
    __shared__ float b1s[64], w2s[128];
    int t = threadIdx.x, b = blockIdx.x;
    for (int i = t; i < 64 * DBP; i += 256) accT[i] = 0.f;
    if (t < DB) hist[t] = 0;
    if (t >= 64 && t < 128) b1s[t - 64] = b1[t - 64];
    else if (t >= 128 && t < 256) w2s[t - 128] = W2[t - 128];
    __syncthreads();
    int cnt = cur_d[b];
    const int* bucket = dpk + b * BCAP_D;
    int w = t >> 6, l = t & 63, e8 = l >> 3, fg = l & 7;
    for (int base = w * 8; base < cnt; base += 32) {
        int j = base + e8;
        if (j < cnt) {
            int pk = bucket[j];
            int s = ((unsigned)pk) >> 5;
            int dlow = pk & 31;
            uint4 u = *(const uint4*)(&hb[(size_t)s * NHID + fg * 8]);
            int a0 = (fg * 8) * DBP + dlow;
            atomicAdd(&accT[a0 + 0 * DBP], bflo(u.x));
            atomicAdd(&accT[a0 + 1 * DBP], bfhi(u.x));
            atomicAdd(&accT[a0 + 2 * DBP], bflo(u.y));
            atomicAdd(&accT[a0 + 3 * DBP], bfhi(u.y));
            atomicAdd(&accT[a0 + 4 * DBP], bflo(u.z));
            atomicAdd(&accT[a0 + 5 * DBP], bfhi(u.z));
            atomicAdd(&accT[a0 + 6 * DBP], bflo(u.w));
            atomicAdd(&accT[a0 + 7 * DBP], bfhi(u.w));
            if (fg == 0) atomicAdd(&hist[dlow], 1);
        }
    }
    __syncthreads();
    if (t < DB) {
        int gnode = b * DB + t;
        if (gnode < N_NODES) {
            float nd = rsqrtf(fmaxf((float)hist[t], 1.0f));
            norm_dst[gnode] = nd;
            float ns = norm_src[gnode];
            float p0 = 0.f, p1 = 0.f;
#pragma unroll
            for (int f = 0; f < 64; ++f) {
                float h1 = fmaxf(fmaf(accT[f * DBP + t], nd, b1s[f]), 0.f) * ns;
                p0 = fmaf(h1, w2s[f * 2], p0);
                p1 = fmaf(h1, w2s[f * 2 + 1], p1);
            }
            *(float2*)(&h2[gnode * 2]) = make_float2(p0, p1);
        }
    }
}

// K5: fused layer2, bucket-major: stream bucket edges, gather h2[src] (8B,
// L2-resident), ds_add into 32x2 LDS tile, log_softmax epilogue.
__global__ __launch_bounds__(256) void fused2_kernel(const int* __restrict__ cur_d,
                                                     const int* __restrict__ dpk,
                                                     const float* __restrict__ h2,
                                                     const float* __restrict__ norm_dst,
                                                     const float* __restrict__ b2,
                                                     float* __restrict__ out) {
    __shared__ float acc2[DB * 2];
    int t = threadIdx.x, b = blockIdx.x;
    if (t < DB * 2) acc2[t] = 0.f;
    __syncthreads();
    int cnt = cur_d[b];
    const int* bucket = dpk + b * BCAP_D;
    for (int j = t; j < cnt; j += 256) {
        int pk = bucket[j];
        int s = ((unsigned)pk) >> 5;
        int dlow = pk & 31;
        float2 v = *(const float2*)(&h2[s * 2]);
        atomicAdd(&acc2[dlow * 2 + 0], v.x);
        atomicAdd(&acc2[dlow * 2 + 1], v.y);
    }
    __syncthreads();
    if (t < DB) {
        int gnode = b * DB + t;
        if (gnode < N_NODES) {
            float nd = norm_dst[gnode];
            float l0 = fmaf(acc2[t * 2 + 0], nd, b2[0]);
            float l1 = fmaf(acc2[t * 2 + 1], nd, b2[1]);
            float m = fmaxf(l0, l1);
            float lse = m + logf(expf(l0 - m) + expf(l1 - m));
            *(float2*)(&out[gnode * 2]) = make_float2(l0 - lse, l1 - lse);
        }
    }
}

extern "C" void kernel_launch(void* const* d_in, const int* in_sizes, int n_in,
                              void* d_out, int out_size, void* d_ws, size_t ws_size,
                              hipStream_t stream) {
    const float* x  = (const float*)d_in[0];
    const int* src  = (const int*)d_in[1];
    const int* dst  = (const int*)d_in[2];
    const float* W1 = (const float*)d_in[3];
    const float* b1 = (const float*)d_in[4];
    const float* W2 = (const float*)d_in[5];
    const float* b2 = (const float*)d_in[6];
    float* out = (float*)d_out;
    float* ws  = (float*)d_ws;
    int*   wsi = (int*)d_ws;

    int*   cur_d    = wsi + OFF_CURD;
    int*   cur_s    = wsi + OFF_CURS;
    float* norm_src = ws + OFF_NSRC;
    float* norm_dst = ws + OFF_NDST;
    int*   dpk      = wsi + OFF_DPK;
    unsigned char* sv8 = (unsigned char*)(wsi + OFF_SV8);
    unsigned short* hb = (unsigned short*)(wsi + OFF_HB);
    float* h2       = ws + OFF_H2;

    hipMemsetAsync(cur_d, 0, (1600 + 256) * sizeof(int), stream);
    bscatter_kernel<<<NB_EDGE, 256, 0, stream>>>(src, dst, cur_d, cur_s, dpk, sv8);
    sfin_kernel<<<NSB, 256, 0, stream>>>(cur_s, sv8, norm_src);
    gemm1_kernel<<<(N_NODES + 63) / 64, 256, 0, stream>>>(x, W1, norm_src, hb);
    fused1_kernel<<<NDB, 256, 0, stream>>>(cur_d, dpk, hb, norm_src, b1, W2, norm_dst, h2);
    fused2_kernel<<<NDB, 256, 0, stream>>>(cur_d, dpk, h2, norm_dst, b2, out);
}

// Round 7
// 189.480 us; speedup vs baseline: 2.6421x; 2.4038x over previous
//
#include <hip/hip_runtime.h>
#include <math.h>

#define N_NODES 50000
#define N_EDGES 800000
#define NFEAT 256
#define NHID 64
#define NCLASS 2

// dst buckets: node>>8 -> 196 buckets of 256 nodes (CSR built per bucket)
#define NBUCK 196
#define BCAP 8192        // mean 4081, sigma 64 -> 64 sigma headroom
#define EPB 2048         // edges per scatter block (8/thread) -> 392 blocks
#define NB_EDGE ((N_EDGES + EPB - 1) / EPB)

// ---------------- workspace layout (4-byte units) ----------------
#define OFF_CURD 0        // int[256]  dst-bucket cursors (memset 0)
#define OFF_CURS 256      // int[256]  src-bucket cursors (memset 0)
#define OFF_RB   512      // int[50000] row_beg
#define OFF_DEG  50512    // int[50000] in-degree
#define OFF_NDST 100512   // f32[50000]
#define OFF_NSRC 150512   // f32[50000]
#define OFF_DPK  200512   // int[196*8192] packed (src<<8|dst&255) by dst>>8
#define OFF_SV8  1806144  // uchar[196*8192] (src&255) by src>>8 = 401408 words
#define OFF_CSR  2207552  // int[196*8192] csr src ids
#define OFF_HB   3813184  // bf16[50000*64] = 1600000 words (16B aligned)
#define OFF_H2   5413184  // f32[100000]

typedef __attribute__((ext_vector_type(8))) short bf16x8;
typedef __attribute__((ext_vector_type(4))) float f32x4;

static __device__ __forceinline__ unsigned short f2bf(float f) {
    union { float f; unsigned int u; } v; v.f = f;
    unsigned int u = v.u + 0x7fffu + ((v.u >> 16) & 1u);  // RNE
    return (unsigned short)(u >> 16);
}
static __device__ __forceinline__ float bflo(unsigned int u) {
    union { unsigned int x; float f; } v; v.x = u << 16; return v.f;
}
static __device__ __forceinline__ float bfhi(unsigned int u) {
    union { unsigned int x; float f; } v; v.x = u & 0xffff0000u; return v.f;
}

// K1: partition edges into fixed-capacity dst-buckets (packed src<<8|dstlow)
// and src-buckets (src&255 bytes). LDS hist -> one global atomic per bucket.
__global__ __launch_bounds__(256) void bscatter_kernel(const int* __restrict__ src,
                                                       const int* __restrict__ dst,
                                                       int* __restrict__ cur_d,
                                                       int* __restrict__ cur_s,
                                                       int* __restrict__ dpk,
                                                       unsigned char* __restrict__ sv8) {
    __shared__ int hd[256], hs[256], bd[256], bs[256], cd[256], cs[256];
    int t = threadIdx.x;
    hd[t] = 0; hs[t] = 0; cd[t] = 0; cs[t] = 0;
    __syncthreads();
    int base = blockIdx.x * EPB;
    int ls[8], ld[8];
#pragma unroll
    for (int i = 0; i < 8; ++i) {
        int e = base + t + i * 256;
        ls[i] = (e < N_EDGES) ? src[e] : -1;
        ld[i] = (e < N_EDGES) ? dst[e] : -1;
        if (ld[i] >= 0) {
            atomicAdd(&hd[ld[i] >> 8], 1);
            atomicAdd(&hs[ls[i] >> 8], 1);
        }
    }
    __syncthreads();
    if (hd[t]) bd[t] = atomicAdd(&cur_d[t], hd[t]);
    if (hs[t]) bs[t] = atomicAdd(&cur_s[t], hs[t]);
    __syncthreads();
#pragma unroll
    for (int i = 0; i < 8; ++i) {
        if (ld[i] >= 0) {
            int bin = ld[i] >> 8;
            int pos = bd[bin] + atomicAdd(&cd[bin], 1);
            dpk[bin * BCAP + pos] = (ls[i] << 8) | (ld[i] & 255);
            int sbin = ls[i] >> 8;
            int spos = bs[sbin] + atomicAdd(&cs[sbin], 1);
            sv8[sbin * BCAP + spos] = (unsigned char)(ls[i] & 255);
        }
    }
}

// K2: per dst-bucket: stage bucket in LDS (one dpk read), in-degree hist ->
// row_beg/deg/norm_dst, scan, rank -> csr. No global atomics.
__global__ __launch_bounds__(256) void dfin_kernel(const int* __restrict__ cur_d,
                                                   const int* __restrict__ dpk,
                                                   int* __restrict__ row_beg,
                                                   int* __restrict__ degv,
                                                   float* __restrict__ norm_dst,
                                                   int* __restrict__ csr) {
    __shared__ int ebuf[BCAP];  // 32 KB
    __shared__ int hist[256], seg[256], cur[256];
    int b = blockIdx.x, t = threadIdx.x;
    int cnt = cur_d[b];
    int base = b * BCAP;
    hist[t] = 0; cur[t] = 0;
    for (int j = t; j < cnt; j += 256) ebuf[j] = dpk[base + j];
    __syncthreads();
    for (int j = t; j < cnt; j += 256) atomicAdd(&hist[ebuf[j] & 255], 1);
    __syncthreads();
    int v = hist[t];
    seg[t] = v;
    __syncthreads();
#pragma unroll
    for (int off = 1; off < 256; off <<= 1) {
        int x = (t >= off) ? seg[t - off] : 0;
        __syncthreads();
        seg[t] += x;
        __syncthreads();
    }
    int excl = seg[t] - v;
    int gid = b * 256 + t;
    if (gid < N_NODES) {
        row_beg[gid] = base + excl;
        degv[gid] = v;
        norm_dst[gid] = rsqrtf(fmaxf((float)v, 1.0f));
    }
    seg[t] = excl;
    __syncthreads();
    for (int j = t; j < cnt; j += 256) {
        int p = ebuf[j];
        int dlow = p & 255;
        int pos = base + seg[dlow] + atomicAdd(&cur[dlow], 1);
        csr[pos] = ((unsigned)p) >> 8;
    }
}

// K3: per src-bucket: out-degree hist -> norm_src
__global__ __launch_bounds__(256) void sfin_kernel(const int* __restrict__ cur_s,
                                                   const unsigned char* __restrict__ sv8,
                                                   float* __restrict__ norm_src) {
    __shared__ int hist[256];
    int b = blockIdx.x, t = threadIdx.x;
    hist[t] = 0;
    __syncthreads();
    int cnt = cur_s[b];
    int base = b * BCAP;
    for (int j = t; j < cnt; j += 256) atomicAdd(&hist[sv8[base + j]], 1);
    __syncthreads();
    int gid = b * 256 + t;
    if (gid < N_NODES) norm_src[gid] = rsqrtf(fmaxf((float)hist[t], 1.0f));
}

// K4: h_bf16[50000x64] = bf16( (x * norm_src[:,None]) @ W1[256x64] ), MFMA
#define LDA 264
__global__ __launch_bounds__(256) void gemm1_kernel(const float* __restrict__ x,
                                                    const float* __restrict__ W1,
                                                    const float* __restrict__ norm_src,
                                                    unsigned short* __restrict__ hb) {
    __shared__ unsigned short As[64][LDA];
    __shared__ unsigned short Bs[64][LDA];
    const int t = threadIdx.x;
    const int row0 = blockIdx.x * 64;
#pragma unroll
    for (int i = 0; i < 16; ++i) {
        int f = i * 256 + t;
        int r = f >> 6;
        int c4 = (f & 63) * 4;
        int grow = row0 + r;
        float4 av = make_float4(0.f, 0.f, 0.f, 0.f);
        float nrm = 0.f;
        if (grow < N_NODES) {
            av = *(const float4*)(&x[(size_t)grow * NFEAT + c4]);
            nrm = norm_src[grow];
        }
        ushort4 o;
        o.x = f2bf(av.x * nrm); o.y = f2bf(av.y * nrm);
        o.z = f2bf(av.z * nrm); o.w = f2bf(av.w * nrm);
        *(ushort4*)(&As[r][c4]) = o;
    }
#pragma unroll
    for (int i = 0; i < 16; ++i) {
        int f = i * 256 + t;
        int k = f >> 4;
        int n4 = (f & 15) * 4;
        float4 wv = *(const float4*)(&W1[k * NHID + n4]);
        Bs[n4 + 0][k] = f2bf(wv.x);
        Bs[n4 + 1][k] = f2bf(wv.y);
        Bs[n4 + 2][k] = f2bf(wv.z);
        Bs[n4 + 3][k] = f2bf(wv.w);
    }
    __syncthreads();
    const int w = t >> 6;
    const int l = t & 63;
    const int m = l & 15;
    const int kq = (l >> 4) * 8;
    f32x4 acc[4] = {{0.f, 0.f, 0.f, 0.f}, {0.f, 0.f, 0.f, 0.f},
                    {0.f, 0.f, 0.f, 0.f}, {0.f, 0.f, 0.f, 0.f}};
#pragma unroll
    for (int c8 = 0; c8 < 8; ++c8) {
        int k0 = c8 * 32 + kq;
        bf16x8 a = *(const bf16x8*)(&As[w * 16 + m][k0]);
#pragma unroll
        for (int ct = 0; ct < 4; ++ct) {
            bf16x8 b = *(const bf16x8*)(&Bs[ct * 16 + m][k0]);
            acc[ct] = __builtin_amdgcn_mfma_f32_16x16x32_bf16(a, b, acc[ct], 0, 0, 0);
        }
    }
    const int q = l >> 4;
#pragma unroll
    for (int ct = 0; ct < 4; ++ct) {
#pragma unroll
        for (int reg = 0; reg < 4; ++reg) {
            int r = row0 + w * 16 + q * 4 + reg;
            if (r < N_NODES) hb[(size_t)r * NHID + ct * 16 + m] = f2bf(acc[ct][reg]);
        }
    }
}

// K5: fused layer1, node-major, register accumulation, 16 edges in flight
// per wave (2 unrolled dwordx4 x 8 edge-slots). lane = e8*8 + fg.
//   acc[k] = sum_edges h_bf16[src][fg*8+k]  (partial over e8 slot)
//   butterfly e8 (8,16,32) -> full agg; epilogue relu/b1/ns/W2;
//   butterfly fg (1,2,4) -> h2[node][0:2]
__global__ __launch_bounds__(256) void fused1_kernel(const int* __restrict__ row_beg,
                                                     const int* __restrict__ degv,
                                                     const int* __restrict__ csr,
                                                     const unsigned short* __restrict__ hb,
                                                     const float* __restrict__ norm_dst,
                                                     const float* __restrict__ norm_src,
                                                     const float* __restrict__ b1,
                                                     const float* __restrict__ W2,
                                                     float* __restrict__ h2) {
    int gtid = blockIdx.x * blockDim.x + threadIdx.x;
    int node = gtid >> 6;
    int lane = gtid & 63;
    if (node >= N_NODES) return;
    int e8 = lane >> 3, fg = lane & 7;
    int beg = row_beg[node];
    int end = beg + degv[node];
    float a0 = 0.f, a1 = 0.f, a2 = 0.f, a3 = 0.f, a4 = 0.f, a5 = 0.f, a6 = 0.f, a7 = 0.f;
    for (int j = beg; j < end; j += 16) {
        int j0 = j + e8, j1 = j0 + 8;
        uint4 u0 = make_uint4(0u, 0u, 0u, 0u), u1 = make_uint4(0u, 0u, 0u, 0u);
        if (j0 < end) u0 = *(const uint4*)(&hb[(size_t)csr[j0] * NHID + fg * 8]);
        if (j1 < end) u1 = *(const uint4*)(&hb[(size_t)csr[j1] * NHID + fg * 8]);
        a0 += bflo(u0.x) + bflo(u1.x);
        a1 += bfhi(u0.x) + bfhi(u1.x);
        a2 += bflo(u0.y) + bflo(u1.y);
        a3 += bfhi(u0.y) + bfhi(u1.y);
        a4 += bflo(u0.z) + bflo(u1.z);
        a5 += bfhi(u0.z) + bfhi(u1.z);
        a6 += bflo(u0.w) + bflo(u1.w);
        a7 += bfhi(u0.w) + bfhi(u1.w);
    }
#pragma unroll
    for (int off = 8; off <= 32; off <<= 1) {
        a0 += __shfl_xor(a0, off, 64);
        a1 += __shfl_xor(a1, off, 64);
        a2 += __shfl_xor(a2, off, 64);
        a3 += __shfl_xor(a3, off, 64);
        a4 += __shfl_xor(a4, off, 64);
        a5 += __shfl_xor(a5, off, 64);
        a6 += __shfl_xor(a6, off, 64);
        a7 += __shfl_xor(a7, off, 64);
    }
    float nd = norm_dst[node], ns = norm_src[node];
    float4 bv0 = *(const float4*)(&b1[fg * 8]);
    float4 bv1 = *(const float4*)(&b1[fg * 8 + 4]);
    // W2 rows for feats fg*8 .. fg*8+7: 16 floats
    float4 w0 = *(const float4*)(&W2[fg * 16 + 0]);
    float4 w1 = *(const float4*)(&W2[fg * 16 + 4]);
    float4 w2v = *(const float4*)(&W2[fg * 16 + 8]);
    float4 w3 = *(const float4*)(&W2[fg * 16 + 12]);
    float h0 = fmaxf(fmaf(a0, nd, bv0.x), 0.f) * ns;
    float h1 = fmaxf(fmaf(a1, nd, bv0.y), 0.f) * ns;
    float h2f = fmaxf(fmaf(a2, nd, bv0.z), 0.f) * ns;
    float h3 = fmaxf(fmaf(a3, nd, bv0.w), 0.f) * ns;
    float h4 = fmaxf(fmaf(a4, nd, bv1.x), 0.f) * ns;
    float h5 = fmaxf(fmaf(a5, nd, bv1.y), 0.f) * ns;
    float h6 = fmaxf(fmaf(a6, nd, bv1.z), 0.f) * ns;
    float h7 = fmaxf(fmaf(a7, nd, bv1.w), 0.f) * ns;
    float p0 = h0 * w0.x + h1 * w0.z + h2f * w1.x + h3 * w1.z +
               h4 * w2v.x + h5 * w2v.z + h6 * w3.x + h7 * w3.z;
    float p1 = h0 * w0.y + h1 * w0.w + h2f * w1.y + h3 * w1.w +
               h4 * w2v.y + h5 * w2v.w + h6 * w3.y + h7 * w3.w;
#pragma unroll
    for (int off = 1; off <= 4; off <<= 1) {
        p0 += __shfl_xor(p0, off, 64);
        p1 += __shfl_xor(p1, off, 64);
    }
    if (lane == 0) *(float2*)(&h2[node * 2]) = make_float2(p0, p1);
}

// K6: fused layer2 per dst node (one thread): agg h2 -> logits -> log_softmax
__global__ void fused2_kernel(const int* __restrict__ row_beg, const int* __restrict__ degv,
                              const int* __restrict__ csr, const float* __restrict__ h2,
                              const float* __restrict__ norm_dst, const float* __restrict__ b2,
                              float* __restrict__ out) {
    int n = blockIdx.x * blockDim.x + threadIdx.x;
    if (n >= N_NODES) return;
    int beg = row_beg[n], end = beg + degv[n];
    float s0 = 0.f, s1 = 0.f;
    for (int j = beg; j < end; ++j) {
        float2 v = *(const float2*)(&h2[csr[j] * 2]);
        s0 += v.x;
        s1 += v.y;
    }
    float nd = norm_dst[n];
    float l0 = fmaf(s0, nd, b2[0]);
    float l1 = fmaf(s1, nd, b2[1]);
    float m = fmaxf(l0, l1);
    float lse = m + logf(expf(l0 - m) + expf(l1 - m));
    *(float2*)(&out[n * 2]) = make_float2(l0 - lse, l1 - lse);
}

extern "C" void kernel_launch(void* const* d_in, const int* in_sizes, int n_in,
                              void* d_out, int out_size, void* d_ws, size_t ws_size,
                              hipStream_t stream) {
    const float* x  = (const float*)d_in[0];
    const int* src  = (const int*)d_in[1];
    const int* dst  = (const int*)d_in[2];
    const float* W1 = (const float*)d_in[3];
    const float* b1 = (const float*)d_in[4];
    const float* W2 = (const float*)d_in[5];
    const float* b2 = (const float*)d_in[6];
    float* out = (float*)d_out;
    float* ws  = (float*)d_ws;
    int*   wsi = (int*)d_ws;

    int*   cur_d    = wsi + OFF_CURD;
    int*   cur_s    = wsi + OFF_CURS;
    int*   row_beg  = wsi + OFF_RB;
    int*   degv     = wsi + OFF_DEG;
    float* norm_dst = ws + OFF_NDST;
    float* norm_src = ws + OFF_NSRC;
    int*   dpk      = wsi + OFF_DPK;
    unsigned char* sv8 = (unsigned char*)(wsi + OFF_SV8);
    int*   csr      = wsi + OFF_CSR;
    unsigned short* hb = (unsigned short*)(wsi + OFF_HB);
    float* h2       = ws + OFF_H2;

    hipMemsetAsync(cur_d, 0, 512 * sizeof(int), stream);
    bscatter_kernel<<<NB_EDGE, 256, 0, stream>>>(src, dst, cur_d, cur_s, dpk, sv8);
    dfin_kernel<<<NBUCK, 256, 0, stream>>>(cur_d, dpk, row_beg, degv, norm_dst, csr);
    sfin_kernel<<<NBUCK, 256, 0, stream>>>(cur_s, sv8, norm_src);
    gemm1_kernel<<<(N_NODES + 63) / 64, 256, 0, stream>>>(x, W1, norm_src, hb);
    {
        long long threads = (long long)N_NODES * 64;
        fused1_kernel<<<(int)((threads + 255) / 256), 256, 0, stream>>>(
            row_beg, degv, csr, hb, norm_dst, norm_src, b1, W2, h2);
    }
    fused2_kernel<<<(N_NODES + 255) / 256, 256, 0, stream>>>(row_beg, degv, csr, h2, norm_dst, b2, out);
}